// Round 4
// baseline (416.734 us; speedup 1.0000x reference)
//
#include <hip/hip_runtime.h>
#include <hip/hip_bf16.h>

// Problem constants (reference: x [64,256,64,64] fp32, keep_num=2048)
#define BB 64
#define CC 256
#define NN 4096          // 64*64 tokens
#define KKEEP 2048
#define CCHUNK 64        // channel chunk per partial-score block (4 chunks)

// ---------------------------------------------------------------------------
// Kernel 1: partial token scores.  P[cy][b][n] = sum_{c in chunk cy} |x[b,c,n]|
// grid = (B*4, 4)  block = 256.  Each thread: 4 tokens (float4), 64 channels.
// 1024 blocks -> 4 blocks/CU -> 16 waves/CU; coalesced 1 KiB/wave/instr.
// ---------------------------------------------------------------------------
__global__ __launch_bounds__(256) void score_partial_kernel(
    const float* __restrict__ x, float* __restrict__ P) {
    const int b  = blockIdx.x >> 2;
    const int ng = blockIdx.x & 3;
    const int cy = blockIdx.y;
    const int n0 = ng * 1024 + threadIdx.x * 4;
    const float* xb = x + (size_t)(b * CC + cy * CCHUNK) * NN + n0;
    float4 acc = make_float4(0.f, 0.f, 0.f, 0.f);
    #pragma unroll 16
    for (int c = 0; c < CCHUNK; ++c) {
        const float4 v = *(const float4*)(xb + (size_t)c * NN);
        acc.x += fabsf(v.x); acc.y += fabsf(v.y);
        acc.z += fabsf(v.z); acc.w += fabsf(v.w);
    }
    *(float4*)(P + (size_t)(cy * BB + b) * NN + n0) = acc;
}

// ---------------------------------------------------------------------------
// Kernel 2: per-batch top-k selection -> 0/1 float mask.
// ONE WAVE per batch (64 blocks x 64 threads) -> zero __syncthreads.
// Lane l holds scores of tokens {64j + l : j in [0,64)} in 64 VGPRs; loads are
// coalesced dwords (256 B/wave/instr) from L2/L3-resident P (4 MB).
// Scores >= 0 so fp32 bit patterns are order-isomorphic to uint32: greedy
// bit-build finds T = max u with count(bits >= u) >= K == k-th largest bits.
// Tie-break matches jax.lax.top_k (lowest index first) via per-group ballot
// prefix in token order.  All reductions are in-wave shuffles.
// ---------------------------------------------------------------------------
__global__ __launch_bounds__(64) void select_kernel(
    const float* __restrict__ P, float* __restrict__ M) {
    const int b = blockIdx.x;
    const int lane = threadIdx.x;   // 0..63

    const float* p0 = P + (size_t)(0 * BB + b) * NN;
    const float* p1 = P + (size_t)(1 * BB + b) * NN;
    const float* p2 = P + (size_t)(2 * BB + b) * NN;
    const float* p3 = P + (size_t)(3 * BB + b) * NN;

    unsigned su[64];
    #pragma unroll
    for (int j = 0; j < 64; ++j) {
        const int n = j * 64 + lane;
        su[j] = __float_as_uint(p0[n] + p1[n] + p2[n] + p3[n]);
    }

    // wave-wide count of scores with bits >= thr (uniform result, no barriers)
    auto count_ge = [&](unsigned thr) -> unsigned {
        unsigned c = 0;
        #pragma unroll
        for (int j = 0; j < 64; ++j) c += (su[j] >= thr) ? 1u : 0u;
        #pragma unroll
        for (int off = 32; off; off >>= 1) c += __shfl_down((int)c, off, 64);
        return (unsigned)__shfl((int)c, 0, 64);   // broadcast lane 0
    };

    unsigned T = 0;
    for (int bit = 31; bit >= 0; --bit) {
        unsigned cand = T | (1u << bit);
        if (count_ge(cand) >= KKEEP) T = cand;
    }
    const unsigned cnt_gt = count_ge(T + 1u);      // strictly greater than T
    const unsigned need_eq = KKEEP - cnt_gt;       // >=1 by maximality of T

    // Emit mask in token order: groups j ascending; within group, lane = token
    // offset, so ballot-prefix by lane gives the token-order rank among ties.
    float* mb = M + (size_t)b * NN;
    unsigned run = 0;                              // #eq seen in tokens < group j
    #pragma unroll
    for (int j = 0; j < 64; ++j) {
        const bool eq = (su[j] == T);
        const bool gt = (su[j] > T);
        const unsigned long long em = __ballot(eq);
        const unsigned pre =
            (unsigned)__builtin_popcountll(em & ((1ull << lane) - 1ull));
        const bool sel = gt || (eq && (run + pre < need_eq));
        mb[j * 64 + lane] = sel ? 1.0f : 0.0f;
        run += (unsigned)__builtin_popcountll(em);
    }
}

// ---------------------------------------------------------------------------
// Kernel 3: out[b][c] = (1/2048) * sum_n mask[b][n] * x[b][c][n]
// One wave per (b,c) row; 4 waves/block; float4 loads (row = 16 KiB).
// Mask rows are reused 256x per batch -> L2 hits; x re-read largely hits the
// 256 MiB L3 that kernel 1 just streamed it through.
// ---------------------------------------------------------------------------
__global__ __launch_bounds__(256) void pool_kernel(
    const float* __restrict__ x, const float* __restrict__ M,
    float* __restrict__ out) {
    const int wave = threadIdx.x >> 6;
    const int lane = threadIdx.x & 63;
    const int row  = blockIdx.x * 4 + wave;   // row = b*CC + c
    const int b    = row >> 8;
    const float* xr = x + (size_t)row * NN;
    const float* mr = M + (size_t)b * NN;
    float acc = 0.f;
    #pragma unroll
    for (int j = 0; j < 16; ++j) {
        const int n = j * 256 + lane * 4;
        const float4 v = *(const float4*)(xr + n);
        const float4 m = *(const float4*)(mr + n);
        acc += v.x * m.x + v.y * m.y + v.z * m.z + v.w * m.w;
    }
    #pragma unroll
    for (int off = 32; off; off >>= 1) acc += __shfl_down(acc, off, 64);
    if (lane == 0) out[row] = acc * (1.0f / 2048.0f);
}

extern "C" void kernel_launch(void* const* d_in, const int* in_sizes, int n_in,
                              void* d_out, int out_size, void* d_ws, size_t ws_size,
                              hipStream_t stream) {
    const float* x = (const float*)d_in[0];
    float* out = (float*)d_out;
    // ws layout: P = [4][64][4096] fp32 partial scores (4 MB), M = [64][4096]
    // fp32 mask (1 MB). Everything read is written first within each call, so
    // the harness's 0xAA re-poison of d_ws is harmless.
    float* P = (float*)d_ws;
    float* M = P + (size_t)4 * BB * NN;

    score_partial_kernel<<<dim3(BB * 4, 4), 256, 0, stream>>>(x, P);
    select_kernel<<<BB, 64, 0, stream>>>(P, M);
    pool_kernel<<<(BB * CC) / 4, 256, 0, stream>>>(x, M, out);
}